// Round 2
// baseline (269.634 us; speedup 1.0000x reference)
//
#include <hip/hip_runtime.h>
#include <math.h>

// Problem constants (MoEGate: B=4,T=4096,C=2048,E=64,K=8)
#define NTOK   16384
#define CDIM   2048
#define NEXP   64
#define TOPK   8
#define TOKB   16            // tokens per block (1 MFMA row-tile)
#define NWAVE  8             // waves per block (in-block k-split factor)
#define GBLK   (NTOK / TOKB) // 1024 blocks

typedef _Float16 f16x8 __attribute__((ext_vector_type(8)));
typedef float    f32x4 __attribute__((ext_vector_type(4)));

// ============================================================================
// Kernel 1: pack W[64][2048] fp32 into f16 hi/lo images in MFMA B-fragment
// order. Entry t = ((s*4 + nt)*64 + lane): 8 f16 for (expert = nt*16+(lane&15),
// k = s*32 + (lane>>4)*8 + j). GEMM lane then loads one contiguous 16B chunk.
// ============================================================================
__global__ __launch_bounds__(256) void pack_w16_kernel(
    const float* __restrict__ W,
    _Float16* __restrict__ Wh, _Float16* __restrict__ Wl)
{
    int t    = blockIdx.x * 256 + threadIdx.x;   // 0..16383
    int lane = t & 63;
    int nt   = (t >> 6) & 3;
    int s    = t >> 8;                           // k32-step, 0..63
    int e    = nt * 16 + (lane & 15);
    int k    = s * 32 + (lane >> 4) * 8;
    const float* src = W + (size_t)e * CDIM + k;
    #pragma unroll
    for (int j = 0; j < 8; j++) {
        float x = src[j];
        _Float16 h = (_Float16)x;                // rte
        Wh[(size_t)t * 8 + j] = h;
        Wl[(size_t)t * 8 + j] = (_Float16)(x - (float)h);
    }
}

__device__ __forceinline__ void split_f16(
    const float4 v0, const float4 v1, f16x8& ah, f16x8& al)
{
    float xr[8] = {v0.x, v0.y, v0.z, v0.w, v1.x, v1.y, v1.z, v1.w};
    #pragma unroll
    for (int j = 0; j < 8; j++) {
        _Float16 h = (_Float16)xr[j];
        ah[j] = h;
        al[j] = (_Float16)(xr[j] - (float)h);    // exact residual
    }
}

// ============================================================================
// Kernel 2 (FUSED): 8-way in-block k-split x 16-token row-tile.
// R9 restructure: the old 32-token block needed 64 KB LDS for partials ->
// 2 blocks/CU (16 waves/CU) and rocprof showed EVERYTHING idle (MfmaUtil 6%,
// VALU 11%, HBM 11%, Occ 39%) = MLP-starved. One tokenset per wave halves
// LDS to 32 KB and VGPRs to ~50: grid 1024 x 512thr = exactly 4 blocks/CU,
// 32 waves/CU (100% slots) under __launch_bounds__(512,8) (64-VGPR cap; the
// 2-tokenset kernel already fit 64, this one is strictly slimmer).
// Per s-step: 2 x-loads (prefetched 1 step ahead) + 8 B-loads (per-nt, L2-hot)
// + 12 MFMAs. Partials meet in 32 KB LDS; wave 0 reduces (w-ascending =
// k-order, matching verified rounds) then runs the verified 16-lane shfl_xor
// top-8 (strict >, lowest index wins ties = JAX). ZERO global atomics.
// ============================================================================
__global__ __launch_bounds__(512, 8) void gate_fused_kernel(
    const float* __restrict__ x,       // [NTOK][CDIM]
    const _Float16* __restrict__ Wh,   // packed image, 256 KB (L2-hot)
    const _Float16* __restrict__ Wl,   // packed image, 256 KB (L2-hot)
    const int*   __restrict__ mask,    // [NTOK]
    const float* __restrict__ gbias,   // [NEXP]
    const float* __restrict__ ebias,   // [NEXP]
    float*       __restrict__ out,     // [2*NTOK*TOPK + 1]
    float*       __restrict__ blockcnt)// [GBLK][NEXP]
{
    __shared__ f32x4 sacc[NWAVE][4][64];     // [wave][nt][lane], 32 KB
    __shared__ unsigned int cnt[NEXP];
    const int tid  = threadIdx.x;
    const int lane = tid & 63;
    const int wid  = tid >> 6;               // 0..7
    if (tid < NEXP) cnt[tid] = 0u;

    const int tok0 = blockIdx.x * TOKB;
    const int col  = lane & 15;              // token row for A / expert col for C
    const int q    = lane >> 4;              // quad
    const float* xp = x + (size_t)(tok0 + col) * CDIM + wid * 256 + q * 8;
    const f16x8* bhp = (const f16x8*)Wh + (size_t)wid * 2048 + lane;
    const f16x8* blp = (const f16x8*)Wl + (size_t)wid * 2048 + lane;

    f32x4 acc[4];
    #pragma unroll
    for (int nt = 0; nt < 4; nt++)
        acc[nt] = (f32x4){0.f, 0.f, 0.f, 0.f};

    // depth-1 software pipeline on the HBM-critical x stream
    float4 a0 = *(const float4*)(xp);
    float4 a1 = *(const float4*)(xp + 4);

    #pragma unroll 2
    for (int s = 0; s < 8; s++) {
        f16x8 ah, al;
        split_f16(a0, a1, ah, al);
        if (s < 7) {                          // prefetch next step's x
            a0 = *(const float4*)(xp + (s + 1) * 32);
            a1 = *(const float4*)(xp + (s + 1) * 32 + 4);
        }
        #pragma unroll
        for (int nt = 0; nt < 4; nt++) {
            f16x8 bh = bhp[s * 256 + nt * 64];
            f16x8 bl = blp[s * 256 + nt * 64];
            acc[nt] = __builtin_amdgcn_mfma_f32_16x16x32_f16(ah, bh, acc[nt], 0, 0, 0);
            acc[nt] = __builtin_amdgcn_mfma_f32_16x16x32_f16(al, bh, acc[nt], 0, 0, 0);
            acc[nt] = __builtin_amdgcn_mfma_f32_16x16x32_f16(ah, bl, acc[nt], 0, 0, 0);
        }
    }

    // ---- stage partial accumulators to LDS (lane-contiguous => conflict-free)
    #pragma unroll
    for (int nt = 0; nt < 4; nt++)
        sacc[wid][nt][lane] = acc[nt];
    __syncthreads();

    // ---- epilogue: wave 0 reduces + top-8 for the block's 16 tokens
    if (wid == 0) {
        f32x4 zv[4];
        #pragma unroll
        for (int nt = 0; nt < 4; nt++) {
            f32x4 s = sacc[0][nt][lane];
            #pragma unroll
            for (int w = 1; w < NWAVE; w++) s += sacc[w][nt][lane]; // k-order
            zv[nt] = s;
        }

        float gb[4], eb[4];
        #pragma unroll
        for (int nt = 0; nt < 4; nt++) {
            gb[nt] = gbias[nt * 16 + col];
            eb[nt] = ebias[nt * 16 + col];
        }

        #pragma unroll
        for (int r = 0; r < 4; r++) {
            const int t = tok0 + q * 4 + r;       // C layout: row = q*4+reg
            float z[4], sel[4];
            #pragma unroll
            for (int nt = 0; nt < 4; nt++) {
                z[nt]   = zv[nt][r] + gb[nt];
                sel[nt] = z[nt] + eb[nt];
            }

            int idxs[TOPK]; float probs[TOPK]; float psum = 0.f;
            #pragma unroll
            for (int rr = 0; rr < TOPK; rr++) {
                float bv = -INFINITY, bz = 0.f; int bidx = 1 << 30;
                #pragma unroll
                for (int nt = 0; nt < 4; nt++)
                    if (sel[nt] > bv) { bv = sel[nt]; bz = z[nt]; bidx = nt * 16 + col; }
                #pragma unroll
                for (int m = 1; m < 16; m <<= 1) {   // xor<16 stays in 16-lane group
                    float ov = __shfl_xor(bv, m);
                    float oz = __shfl_xor(bz, m);
                    int   oi = __shfl_xor(bidx, m);
                    if (ov > bv || (ov == bv && oi < bidx)) { bv = ov; bz = oz; bidx = oi; }
                }
                idxs[rr] = bidx;
                float p = 1.f / (1.f + expf(-bz));
                probs[rr] = p; psum += p;
                if ((bidx & 15) == col) sel[bidx >> 4] = -INFINITY;   // mark used
            }
            float inv = 1.f / psum;
            if (col < TOPK) {
                out[(size_t)t * TOPK + col] = (float)idxs[col];
                out[(size_t)NTOK * TOPK + (size_t)t * TOPK + col] = probs[col] * inv;
                if (mask[t] != 0) atomicAdd(&cnt[idxs[col]], 1u);
            }
        }
    }
    __syncthreads();
    if (tid < NEXP)
        blockcnt[(size_t)blockIdx.x * NEXP + tid] = (float)cnt[tid];
}

// ============================================================================
// Kernel 3: tree-sum per-block counts -> maxvio. One block, 256 threads.
// ============================================================================
__global__ __launch_bounds__(256) void finalize_kernel(
    const float* __restrict__ blockcnt, float* __restrict__ out)
{
    __shared__ float ps[4][NEXP];
    const int t = threadIdx.x;
    const int e = t & 63, c = t >> 6;
    float s = 0.f;
    #pragma unroll 8
    for (int b = 0; b < GBLK / 4; b++)
        s += blockcnt[(size_t)(c * (GBLK / 4) + b) * NEXP + e];
    ps[c][e] = s;
    __syncthreads();
    if (t < 64) {
        float tot = ps[0][t] + ps[1][t] + ps[2][t] + ps[3][t];
        float mx = tot, sm = tot;
        #pragma unroll
        for (int o = 32; o > 0; o >>= 1) {
            mx = fmaxf(mx, __shfl_down(mx, o));
            sm += __shfl_down(sm, o);
        }
        if (t == 0) {
            float avg = sm / (float)NEXP;
            out[2 * NTOK * TOPK] = (mx - avg) / (avg + 1e-5f);
        }
    }
}

// ============================================================================
// Fallback for tiny workspace: R1 fused fp32 kernel (known-correct).
// ============================================================================
__global__ __launch_bounds__(256) void fused_fallback_kernel(
    const float* __restrict__ x, const int* __restrict__ mask,
    const float* __restrict__ W, const float* __restrict__ gbias,
    const float* __restrict__ ebias, float* __restrict__ out,
    unsigned int* __restrict__ counts)
{
    __shared__ float As[64][36];
    __shared__ float Bs[64][36];
    __shared__ float Lg[64][NEXP + 1];
    __shared__ float s_gb[NEXP], s_eb[NEXP];
    __shared__ unsigned int s_cnt[NEXP];
    const int tid = threadIdx.x;
    const int tx = tid & 15, ty = tid >> 4;
    const int m0 = blockIdx.x * 64;
    if (tid < NEXP) { s_gb[tid] = gbias[tid]; s_eb[tid] = ebias[tid]; s_cnt[tid] = 0u; }
    float acc[4][4] = {};
    for (int kb = 0; kb < CDIM; kb += 32) {
        __syncthreads();
        #pragma unroll
        for (int p = 0; p < 2; p++) {
            int lin = tid + p * 256; int m = lin >> 3; int c4 = (lin & 7) << 2;
            *(float4*)&As[m][c4] = *(const float4*)&x[(size_t)(m0 + m) * CDIM + kb + c4];
            *(float4*)&Bs[m][c4] = *(const float4*)&W[(size_t)m * CDIM + kb + c4];
        }
        __syncthreads();
        #pragma unroll
        for (int k4 = 0; k4 < 32; k4 += 4) {
            float4 a[4], b[4];
            #pragma unroll
            for (int i = 0; i < 4; i++) a[i] = *(const float4*)&As[ty * 4 + i][k4];
            #pragma unroll
            for (int j = 0; j < 4; j++) b[j] = *(const float4*)&Bs[tx * 4 + j][k4];
            #pragma unroll
            for (int i = 0; i < 4; i++)
                #pragma unroll
                for (int j = 0; j < 4; j++)
                    acc[i][j] += a[i].x * b[j].x + a[i].y * b[j].y
                               + a[i].z * b[j].z + a[i].w * b[j].w;
        }
    }
    __syncthreads();
    #pragma unroll
    for (int i = 0; i < 4; i++)
        #pragma unroll
        for (int j = 0; j < 4; j++)
            Lg[ty * 4 + i][tx * 4 + j] = acc[i][j] + s_gb[tx * 4 + j];
    __syncthreads();
    if (tid < 64) {
        const int g = m0 + tid;
        unsigned long long used = 0ull;
        int idxs[TOPK]; float probs[TOPK]; float psum = 0.f;
        #pragma unroll
        for (int k = 0; k < TOPK; k++) {
            float best = -INFINITY; int bi = 0;
            for (int n = 0; n < NEXP; n++) {
                if ((used >> n) & 1ull) continue;
                float vv = Lg[tid][n] + s_eb[n];
                if (vv > best) { best = vv; bi = n; }
            }
            used |= (1ull << bi);
            idxs[k] = bi;
            float p = 1.f / (1.f + expf(-Lg[tid][bi]));
            probs[k] = p; psum += p;
        }
        float inv = 1.f / psum;
        #pragma unroll
        for (int k = 0; k < TOPK; k++) {
            out[(size_t)g * TOPK + k] = (float)idxs[k];
            out[(size_t)NTOK * TOPK + (size_t)g * TOPK + k] = probs[k] * inv;
        }
        if (mask[g] != 0)
            #pragma unroll
            for (int k = 0; k < TOPK; k++) atomicAdd(&s_cnt[idxs[k]], 1u);
    }
    __syncthreads();
    if (tid < NEXP && s_cnt[tid] != 0u) atomicAdd(&counts[tid], s_cnt[tid]);
}

__global__ void finalize_atomic_kernel(const unsigned int* __restrict__ counts,
                                       float* __restrict__ out)
{
    const int t = threadIdx.x;
    float c  = (float)counts[t];
    float mx = c, sm = c;
    #pragma unroll
    for (int o = 32; o > 0; o >>= 1) {
        mx = fmaxf(mx, __shfl_down(mx, o));
        sm += __shfl_down(sm, o);
    }
    if (t == 0) {
        float avg = sm / (float)NEXP;
        out[2 * NTOK * TOPK] = (mx - avg) / (avg + 1e-5f);
    }
}

extern "C" void kernel_launch(void* const* d_in, const int* in_sizes, int n_in,
                              void* d_out, int out_size, void* d_ws, size_t ws_size,
                              hipStream_t stream)
{
    const float* x     = (const float*)d_in[0];
    const int*   mask  = (const int*)  d_in[1];
    const float* W     = (const float*)d_in[2];
    const float* gbias = (const float*)d_in[3];
    const float* ebias = (const float*)d_in[4];
    float* out = (float*)d_out;

    // ws layout: [Wh 256KB][Wl 256KB][blockcnt 256KB]
    const size_t whB  = (size_t)NEXP * CDIM * sizeof(_Float16);   // 256 KB
    const size_t bcB  = (size_t)GBLK * NEXP * sizeof(float);      // 256 KB
    const size_t need = 2 * whB + bcB;

    if (ws_size >= need) {
        _Float16* Wh = (_Float16*)d_ws;
        _Float16* Wl = (_Float16*)((char*)d_ws + whB);
        float* blockcnt = (float*)((char*)d_ws + 2 * whB);

        pack_w16_kernel<<<64, 256, 0, stream>>>(W, Wh, Wl);
        gate_fused_kernel<<<GBLK, 512, 0, stream>>>(x, Wh, Wl, mask, gbias, ebias, out, blockcnt);
        finalize_kernel<<<1, 256, 0, stream>>>(blockcnt, out);
        return;
    }

    // Fallback: fused fp32 kernel + global-atomic counts
    unsigned int* counts = (unsigned int*)d_ws;
    hipMemsetAsync(d_ws, 0, NEXP * sizeof(unsigned int), stream);
    fused_fallback_kernel<<<NTOK / 64, 256, 0, stream>>>(x, mask, W, gbias, ebias, out, counts);
    finalize_atomic_kernel<<<1, 64, 0, stream>>>(counts, out);
}

// Round 3
// 257.783 us; speedup vs baseline: 1.0460x; 1.0460x over previous
//
#include <hip/hip_runtime.h>
#include <math.h>

// Problem constants (MoEGate: B=4,T=4096,C=2048,E=64,K=8)
#define NTOK   16384
#define CDIM   2048
#define NEXP   64
#define TOPK   8
#define TOKB   16            // tokens per block (1 MFMA row-tile)
#define NWAVE  8             // waves per block (in-block k-split factor)
#define GBLK   (NTOK / TOKB) // 1024 blocks

typedef _Float16 f16x8 __attribute__((ext_vector_type(8)));
typedef float    f32x4 __attribute__((ext_vector_type(4)));

// ============================================================================
// Kernel 1: pack W[64][2048] fp32 into f16 hi/lo images in MFMA B-fragment
// order. Entry t = ((s*4 + nt)*64 + lane): 8 f16 for (expert = nt*16+(lane&15),
// k = s*32 + (lane>>4)*8 + j). GEMM lane then loads one contiguous 16B chunk.
// ============================================================================
__global__ __launch_bounds__(256) void pack_w16_kernel(
    const float* __restrict__ W,
    _Float16* __restrict__ Wh, _Float16* __restrict__ Wl)
{
    int t    = blockIdx.x * 256 + threadIdx.x;   // 0..16383
    int lane = t & 63;
    int nt   = (t >> 6) & 3;
    int s    = t >> 8;                           // k32-step, 0..63
    int e    = nt * 16 + (lane & 15);
    int k    = s * 32 + (lane >> 4) * 8;
    const float* src = W + (size_t)e * CDIM + k;
    #pragma unroll
    for (int j = 0; j < 8; j++) {
        float x = src[j];
        _Float16 h = (_Float16)x;                // rte
        Wh[(size_t)t * 8 + j] = h;
        Wl[(size_t)t * 8 + j] = (_Float16)(x - (float)h);
    }
}

__device__ __forceinline__ void split_f16(
    const float4 v0, const float4 v1, f16x8& ah, f16x8& al)
{
    float xr[8] = {v0.x, v0.y, v0.z, v0.w, v1.x, v1.y, v1.z, v1.w};
    #pragma unroll
    for (int j = 0; j < 8; j++) {
        _Float16 h = (_Float16)xr[j];
        ah[j] = h;
        al[j] = (_Float16)(xr[j] - (float)h);    // exact residual
    }
}

// ============================================================================
// Kernel 2 (FUSED): 8-way in-block k-split x 16-token row-tile.
// R10: R9's one-tokenset restructure (LDS 66->33 KB) was right, but pairing it
// with __launch_bounds__(512,8) re-triggered the documented R8 failure: the
// 64-VGPR cap spilled the main loop (VGPR_Count=32, WRITE_SIZE 35.5 MB of
// scratch, dur 116 us — identical to R8's note). Revert the bound to (512,4)
// (128-VGPR cap): round-0 evidence shows the allocator settles at 64 VGPRs
// spill-free under this bound on a FATTER kernel, so this slimmer one fits
// <=64. Runtime occupancy is set by ACTUAL usage: 64 VGPR -> 8 waves/SIMD,
// 33 KB LDS -> 4 blocks/CU -> up to 32 waves/CU, grid 1024 = 4 blocks/CU.
// Per s-step: 2 x-loads (prefetched 1 step ahead) + 8 B-loads (L2-hot)
// + 12 MFMAs. Partials meet in 32 KB LDS; wave 0 reduces (w-ascending =
// k-order, matching verified rounds) then runs the verified 16-lane shfl_xor
// top-8 (strict >, lowest index wins ties = JAX). ZERO global atomics.
// ============================================================================
__global__ __launch_bounds__(512, 4) void gate_fused_kernel(
    const float* __restrict__ x,       // [NTOK][CDIM]
    const _Float16* __restrict__ Wh,   // packed image, 256 KB (L2-hot)
    const _Float16* __restrict__ Wl,   // packed image, 256 KB (L2-hot)
    const int*   __restrict__ mask,    // [NTOK]
    const float* __restrict__ gbias,   // [NEXP]
    const float* __restrict__ ebias,   // [NEXP]
    float*       __restrict__ out,     // [2*NTOK*TOPK + 1]
    float*       __restrict__ blockcnt)// [GBLK][NEXP]
{
    __shared__ f32x4 sacc[NWAVE][4][64];     // [wave][nt][lane], 32 KB
    __shared__ unsigned int cnt[NEXP];
    const int tid  = threadIdx.x;
    const int lane = tid & 63;
    const int wid  = tid >> 6;               // 0..7
    if (tid < NEXP) cnt[tid] = 0u;

    const int tok0 = blockIdx.x * TOKB;
    const int col  = lane & 15;              // token row for A / expert col for C
    const int q    = lane >> 4;              // quad
    const float* xp = x + (size_t)(tok0 + col) * CDIM + wid * 256 + q * 8;
    const f16x8* bhp = (const f16x8*)Wh + (size_t)wid * 2048 + lane;
    const f16x8* blp = (const f16x8*)Wl + (size_t)wid * 2048 + lane;

    f32x4 acc[4];
    #pragma unroll
    for (int nt = 0; nt < 4; nt++)
        acc[nt] = (f32x4){0.f, 0.f, 0.f, 0.f};

    // depth-1 software pipeline on the HBM-critical x stream
    float4 a0 = *(const float4*)(xp);
    float4 a1 = *(const float4*)(xp + 4);

    #pragma unroll 2
    for (int s = 0; s < 8; s++) {
        f16x8 ah, al;
        split_f16(a0, a1, ah, al);
        if (s < 7) {                          // prefetch next step's x
            a0 = *(const float4*)(xp + (s + 1) * 32);
            a1 = *(const float4*)(xp + (s + 1) * 32 + 4);
        }
        #pragma unroll
        for (int nt = 0; nt < 4; nt++) {
            f16x8 bh = bhp[s * 256 + nt * 64];
            f16x8 bl = blp[s * 256 + nt * 64];
            acc[nt] = __builtin_amdgcn_mfma_f32_16x16x32_f16(ah, bh, acc[nt], 0, 0, 0);
            acc[nt] = __builtin_amdgcn_mfma_f32_16x16x32_f16(al, bh, acc[nt], 0, 0, 0);
            acc[nt] = __builtin_amdgcn_mfma_f32_16x16x32_f16(ah, bl, acc[nt], 0, 0, 0);
        }
    }

    // ---- stage partial accumulators to LDS (lane-contiguous => conflict-free)
    #pragma unroll
    for (int nt = 0; nt < 4; nt++)
        sacc[wid][nt][lane] = acc[nt];
    __syncthreads();

    // ---- epilogue: wave 0 reduces + top-8 for the block's 16 tokens
    if (wid == 0) {
        f32x4 zv[4];
        #pragma unroll
        for (int nt = 0; nt < 4; nt++) {
            f32x4 s = sacc[0][nt][lane];
            #pragma unroll
            for (int w = 1; w < NWAVE; w++) s += sacc[w][nt][lane]; // k-order
            zv[nt] = s;
        }

        float gb[4], eb[4];
        #pragma unroll
        for (int nt = 0; nt < 4; nt++) {
            gb[nt] = gbias[nt * 16 + col];
            eb[nt] = ebias[nt * 16 + col];
        }

        #pragma unroll
        for (int r = 0; r < 4; r++) {
            const int t = tok0 + q * 4 + r;       // C layout: row = q*4+reg
            float z[4], sel[4];
            #pragma unroll
            for (int nt = 0; nt < 4; nt++) {
                z[nt]   = zv[nt][r] + gb[nt];
                sel[nt] = z[nt] + eb[nt];
            }

            int idxs[TOPK]; float probs[TOPK]; float psum = 0.f;
            #pragma unroll
            for (int rr = 0; rr < TOPK; rr++) {
                float bv = -INFINITY, bz = 0.f; int bidx = 1 << 30;
                #pragma unroll
                for (int nt = 0; nt < 4; nt++)
                    if (sel[nt] > bv) { bv = sel[nt]; bz = z[nt]; bidx = nt * 16 + col; }
                #pragma unroll
                for (int m = 1; m < 16; m <<= 1) {   // xor<16 stays in 16-lane group
                    float ov = __shfl_xor(bv, m);
                    float oz = __shfl_xor(bz, m);
                    int   oi = __shfl_xor(bidx, m);
                    if (ov > bv || (ov == bv && oi < bidx)) { bv = ov; bz = oz; bidx = oi; }
                }
                idxs[rr] = bidx;
                float p = 1.f / (1.f + expf(-bz));
                probs[rr] = p; psum += p;
                if ((bidx & 15) == col) sel[bidx >> 4] = -INFINITY;   // mark used
            }
            float inv = 1.f / psum;
            if (col < TOPK) {
                out[(size_t)t * TOPK + col] = (float)idxs[col];
                out[(size_t)NTOK * TOPK + (size_t)t * TOPK + col] = probs[col] * inv;
                if (mask[t] != 0) atomicAdd(&cnt[idxs[col]], 1u);
            }
        }
    }
    __syncthreads();
    if (tid < NEXP)
        blockcnt[(size_t)blockIdx.x * NEXP + tid] = (float)cnt[tid];
}

// ============================================================================
// Kernel 3: tree-sum per-block counts -> maxvio. One block, 256 threads.
// ============================================================================
__global__ __launch_bounds__(256) void finalize_kernel(
    const float* __restrict__ blockcnt, float* __restrict__ out)
{
    __shared__ float ps[4][NEXP];
    const int t = threadIdx.x;
    const int e = t & 63, c = t >> 6;
    float s = 0.f;
    #pragma unroll 8
    for (int b = 0; b < GBLK / 4; b++)
        s += blockcnt[(size_t)(c * (GBLK / 4) + b) * NEXP + e];
    ps[c][e] = s;
    __syncthreads();
    if (t < 64) {
        float tot = ps[0][t] + ps[1][t] + ps[2][t] + ps[3][t];
        float mx = tot, sm = tot;
        #pragma unroll
        for (int o = 32; o > 0; o >>= 1) {
            mx = fmaxf(mx, __shfl_down(mx, o));
            sm += __shfl_down(sm, o);
        }
        if (t == 0) {
            float avg = sm / (float)NEXP;
            out[2 * NTOK * TOPK] = (mx - avg) / (avg + 1e-5f);
        }
    }
}

// ============================================================================
// Fallback for tiny workspace: R1 fused fp32 kernel (known-correct).
// ============================================================================
__global__ __launch_bounds__(256) void fused_fallback_kernel(
    const float* __restrict__ x, const int* __restrict__ mask,
    const float* __restrict__ W, const float* __restrict__ gbias,
    const float* __restrict__ ebias, float* __restrict__ out,
    unsigned int* __restrict__ counts)
{
    __shared__ float As[64][36];
    __shared__ float Bs[64][36];
    __shared__ float Lg[64][NEXP + 1];
    __shared__ float s_gb[NEXP], s_eb[NEXP];
    __shared__ unsigned int s_cnt[NEXP];
    const int tid = threadIdx.x;
    const int tx = tid & 15, ty = tid >> 4;
    const int m0 = blockIdx.x * 64;
    if (tid < NEXP) { s_gb[tid] = gbias[tid]; s_eb[tid] = ebias[tid]; s_cnt[tid] = 0u; }
    float acc[4][4] = {};
    for (int kb = 0; kb < CDIM; kb += 32) {
        __syncthreads();
        #pragma unroll
        for (int p = 0; p < 2; p++) {
            int lin = tid + p * 256; int m = lin >> 3; int c4 = (lin & 7) << 2;
            *(float4*)&As[m][c4] = *(const float4*)&x[(size_t)(m0 + m) * CDIM + kb + c4];
            *(float4*)&Bs[m][c4] = *(const float4*)&W[(size_t)m * CDIM + kb + c4];
        }
        __syncthreads();
        #pragma unroll
        for (int k4 = 0; k4 < 32; k4 += 4) {
            float4 a[4], b[4];
            #pragma unroll
            for (int i = 0; i < 4; i++) a[i] = *(const float4*)&As[ty * 4 + i][k4];
            #pragma unroll
            for (int j = 0; j < 4; j++) b[j] = *(const float4*)&Bs[tx * 4 + j][k4];
            #pragma unroll
            for (int i = 0; i < 4; i++)
                #pragma unroll
                for (int j = 0; j < 4; j++)
                    acc[i][j] += a[i].x * b[j].x + a[i].y * b[j].y
                               + a[i].z * b[j].z + a[i].w * b[j].w;
        }
    }
    __syncthreads();
    #pragma unroll
    for (int i = 0; i < 4; i++)
        #pragma unroll
        for (int j = 0; j < 4; j++)
            Lg[ty * 4 + i][tx * 4 + j] = acc[i][j] + s_gb[tx * 4 + j];
    __syncthreads();
    if (tid < 64) {
        const int g = m0 + tid;
        unsigned long long used = 0ull;
        int idxs[TOPK]; float probs[TOPK]; float psum = 0.f;
        #pragma unroll
        for (int k = 0; k < TOPK; k++) {
            float best = -INFINITY; int bi = 0;
            for (int n = 0; n < NEXP; n++) {
                if ((used >> n) & 1ull) continue;
                float vv = Lg[tid][n] + s_eb[n];
                if (vv > best) { best = vv; bi = n; }
            }
            used |= (1ull << bi);
            idxs[k] = bi;
            float p = 1.f / (1.f + expf(-Lg[tid][bi]));
            probs[k] = p; psum += p;
        }
        float inv = 1.f / psum;
        #pragma unroll
        for (int k = 0; k < TOPK; k++) {
            out[(size_t)g * TOPK + k] = (float)idxs[k];
            out[(size_t)NTOK * TOPK + (size_t)g * TOPK + k] = probs[k] * inv;
        }
        if (mask[g] != 0)
            #pragma unroll
            for (int k = 0; k < TOPK; k++) atomicAdd(&s_cnt[idxs[k]], 1u);
    }
    __syncthreads();
    if (tid < NEXP && s_cnt[tid] != 0u) atomicAdd(&counts[tid], s_cnt[tid]);
}

__global__ void finalize_atomic_kernel(const unsigned int* __restrict__ counts,
                                       float* __restrict__ out)
{
    const int t = threadIdx.x;
    float c  = (float)counts[t];
    float mx = c, sm = c;
    #pragma unroll
    for (int o = 32; o > 0; o >>= 1) {
        mx = fmaxf(mx, __shfl_down(mx, o));
        sm += __shfl_down(sm, o);
    }
    if (t == 0) {
        float avg = sm / (float)NEXP;
        out[2 * NTOK * TOPK] = (mx - avg) / (avg + 1e-5f);
    }
}

extern "C" void kernel_launch(void* const* d_in, const int* in_sizes, int n_in,
                              void* d_out, int out_size, void* d_ws, size_t ws_size,
                              hipStream_t stream)
{
    const float* x     = (const float*)d_in[0];
    const int*   mask  = (const int*)  d_in[1];
    const float* W     = (const float*)d_in[2];
    const float* gbias = (const float*)d_in[3];
    const float* ebias = (const float*)d_in[4];
    float* out = (float*)d_out;

    // ws layout: [Wh 256KB][Wl 256KB][blockcnt 256KB]
    const size_t whB  = (size_t)NEXP * CDIM * sizeof(_Float16);   // 256 KB
    const size_t bcB  = (size_t)GBLK * NEXP * sizeof(float);      // 256 KB
    const size_t need = 2 * whB + bcB;

    if (ws_size >= need) {
        _Float16* Wh = (_Float16*)d_ws;
        _Float16* Wl = (_Float16*)((char*)d_ws + whB);
        float* blockcnt = (float*)((char*)d_ws + 2 * whB);

        pack_w16_kernel<<<64, 256, 0, stream>>>(W, Wh, Wl);
        gate_fused_kernel<<<GBLK, 512, 0, stream>>>(x, Wh, Wl, mask, gbias, ebias, out, blockcnt);
        finalize_kernel<<<1, 256, 0, stream>>>(blockcnt, out);
        return;
    }

    // Fallback: fused fp32 kernel + global-atomic counts
    unsigned int* counts = (unsigned int*)d_ws;
    hipMemsetAsync(d_ws, 0, NEXP * sizeof(unsigned int), stream);
    fused_fallback_kernel<<<NTOK / 64, 256, 0, stream>>>(x, mask, W, gbias, ebias, out, counts);
    finalize_atomic_kernel<<<1, 64, 0, stream>>>(counts, out);
}

// Round 4
// 232.112 us; speedup vs baseline: 1.1617x; 1.1106x over previous
//
#include <hip/hip_runtime.h>
#include <math.h>

// Problem constants (MoEGate: B=4,T=4096,C=2048,E=64,K=8)
#define NTOK   16384
#define CDIM   2048
#define NEXP   64
#define TOPK   8
#define TOKB   32            // tokens per block (2 MFMA row-tiles)
#define NWAVE  8             // waves per block (in-block k-split factor)
#define GBLK   (NTOK / TOKB) // 512 blocks

typedef _Float16 f16x8 __attribute__((ext_vector_type(8)));
typedef float    f32x4 __attribute__((ext_vector_type(4)));

// ============================================================================
// Kernel 1: pack W[64][2048] fp32 into f16 hi/lo images in MFMA B-fragment
// order. Entry t = ((s*4 + nt)*64 + lane): 8 f16 for (expert = nt*16+(lane&15),
// k = s*32 + (lane>>4)*8 + j). GEMM lane then loads one contiguous 16B chunk.
// ============================================================================
__global__ __launch_bounds__(256) void pack_w16_kernel(
    const float* __restrict__ W,
    _Float16* __restrict__ Wh, _Float16* __restrict__ Wl)
{
    int t    = blockIdx.x * 256 + threadIdx.x;   // 0..16383
    int lane = t & 63;
    int nt   = (t >> 6) & 3;
    int s    = t >> 8;                           // k32-step, 0..63
    int e    = nt * 16 + (lane & 15);
    int k    = s * 32 + (lane >> 4) * 8;
    const float* src = W + (size_t)e * CDIM + k;
    #pragma unroll
    for (int j = 0; j < 8; j++) {
        float x = src[j];
        _Float16 h = (_Float16)x;                // rte
        Wh[(size_t)t * 8 + j] = h;
        Wl[(size_t)t * 8 + j] = (_Float16)(x - (float)h);
    }
}

__device__ __forceinline__ void split_f16(
    const float4 v0, const float4 v1, f16x8& ah, f16x8& al)
{
    float xr[8] = {v0.x, v0.y, v0.z, v0.w, v1.x, v1.y, v1.z, v1.w};
    #pragma unroll
    for (int j = 0; j < 8; j++) {
        _Float16 h = (_Float16)xr[j];
        ah[j] = h;
        al[j] = (_Float16)(xr[j] - (float)h);    // exact residual
    }
}

// ============================================================================
// Kernel 2 (FUSED): 8-way in-block k-split x 32-token row-tile.
// R11: back to the verified R0 structure (2 tokensets/wave = 24 MFMA / 12
// loads per s-step, 79 us) after R9/R10 proved 1-tokenset is per-wave-ILP
// starved (113 us at the SAME ~16 waves/CU residency; the unified-RF register
// class, not LDS, caps residency, and <=64 total regs is infeasible here).
// New in R11: explicit 2-step-deep software pipeline on the x stream (R0's
// effective lead was <=1 step ~270-540 cy vs ~600-900 cy x latency -> every
// step stalled). W-frag loads are hoisted ahead of the split VALU; K-loop
// fully unrolled so the scheduler can pipeline under the 128-VGPR cap of
// __launch_bounds__(512,4). Prefetch regs: 8 float4 = 32; est total ~110.
// Partials meet in 64 KB LDS (lane-contiguous, conflict-free); waves 0 and 1
// each reduce one tokenset (w-ascending = k-order, matching verified rounds)
// then run the verified 16-lane shfl_xor top-8 (strict >, lowest index wins
// ties = JAX). ZERO global atomics.
// ============================================================================
__global__ __launch_bounds__(512, 4) void gate_fused_kernel(
    const float* __restrict__ x,       // [NTOK][CDIM]
    const _Float16* __restrict__ Wh,   // packed image, 256 KB (L2-hot)
    const _Float16* __restrict__ Wl,   // packed image, 256 KB (L2-hot)
    const int*   __restrict__ mask,    // [NTOK]
    const float* __restrict__ gbias,   // [NEXP]
    const float* __restrict__ ebias,   // [NEXP]
    float*       __restrict__ out,     // [2*NTOK*TOPK + 1]
    float*       __restrict__ blockcnt)// [GBLK][NEXP]
{
    __shared__ f32x4 sacc[NWAVE][2][4][64];  // [wave][tokenset][nt][lane], 64 KB
    __shared__ unsigned int cnt[NEXP];
    const int tid  = threadIdx.x;
    const int lane = tid & 63;
    const int wid  = tid >> 6;               // 0..7
    if (tid < NEXP) cnt[tid] = 0u;

    const int tok0 = blockIdx.x * TOKB;
    const int col  = lane & 15;              // token row for A / expert col for C
    const int q    = lane >> 4;              // quad
    const float* xpA = x + (size_t)(tok0 + col) * CDIM + wid * 256 + q * 8;
    const float* xpB = xpA + (size_t)16 * CDIM;
    const f16x8* bhp = (const f16x8*)Wh + (size_t)wid * 2048 + lane;
    const f16x8* blp = (const f16x8*)Wl + (size_t)wid * 2048 + lane;

    f32x4 accA[4], accB[4];
    #pragma unroll
    for (int nt = 0; nt < 4; nt++) {
        accA[nt] = (f32x4){0.f, 0.f, 0.f, 0.f};
        accB[nt] = (f32x4){0.f, 0.f, 0.f, 0.f};
    }

    // ---- 2-step-deep x prefetch: p* = step s, q* = step s+1 (static names,
    // no runtime-indexed buffers -> no scratch)
    float4 pA0 = *(const float4*)(xpA +  0), pA1 = *(const float4*)(xpA +  4);
    float4 pB0 = *(const float4*)(xpB +  0), pB1 = *(const float4*)(xpB +  4);
    float4 qA0 = *(const float4*)(xpA + 32), qA1 = *(const float4*)(xpA + 36);
    float4 qB0 = *(const float4*)(xpB + 32), qB1 = *(const float4*)(xpB + 36);

    #pragma unroll
    for (int s = 0; s < 8; s += 2) {
        // ======== even step: consume p*, refill p* with step s+2 ========
        f16x8 bh0[4], bl0[4];
        #pragma unroll
        for (int nt = 0; nt < 4; nt++) {     // W loads issued before split VALU
            bh0[nt] = bhp[s * 256 + nt * 64];
            bl0[nt] = blp[s * 256 + nt * 64];
        }
        f16x8 ahA, alA, ahB, alB;
        split_f16(pA0, pA1, ahA, alA);
        split_f16(pB0, pB1, ahB, alB);
        if (s + 2 < 8) {
            pA0 = *(const float4*)(xpA + (s + 2) * 32);
            pA1 = *(const float4*)(xpA + (s + 2) * 32 + 4);
            pB0 = *(const float4*)(xpB + (s + 2) * 32);
            pB1 = *(const float4*)(xpB + (s + 2) * 32 + 4);
        }
        #pragma unroll
        for (int nt = 0; nt < 4; nt++) {
            accA[nt] = __builtin_amdgcn_mfma_f32_16x16x32_f16(ahA, bh0[nt], accA[nt], 0, 0, 0);
            accA[nt] = __builtin_amdgcn_mfma_f32_16x16x32_f16(alA, bh0[nt], accA[nt], 0, 0, 0);
            accA[nt] = __builtin_amdgcn_mfma_f32_16x16x32_f16(ahA, bl0[nt], accA[nt], 0, 0, 0);
            accB[nt] = __builtin_amdgcn_mfma_f32_16x16x32_f16(ahB, bh0[nt], accB[nt], 0, 0, 0);
            accB[nt] = __builtin_amdgcn_mfma_f32_16x16x32_f16(alB, bh0[nt], accB[nt], 0, 0, 0);
            accB[nt] = __builtin_amdgcn_mfma_f32_16x16x32_f16(ahB, bl0[nt], accB[nt], 0, 0, 0);
        }

        // ======== odd step: consume q*, refill q* with step s+3 ========
        f16x8 bh1[4], bl1[4];
        #pragma unroll
        for (int nt = 0; nt < 4; nt++) {
            bh1[nt] = bhp[(s + 1) * 256 + nt * 64];
            bl1[nt] = blp[(s + 1) * 256 + nt * 64];
        }
        split_f16(qA0, qA1, ahA, alA);
        split_f16(qB0, qB1, ahB, alB);
        if (s + 3 < 8) {
            qA0 = *(const float4*)(xpA + (s + 3) * 32);
            qA1 = *(const float4*)(xpA + (s + 3) * 32 + 4);
            qB0 = *(const float4*)(xpB + (s + 3) * 32);
            qB1 = *(const float4*)(xpB + (s + 3) * 32 + 4);
        }
        #pragma unroll
        for (int nt = 0; nt < 4; nt++) {
            accA[nt] = __builtin_amdgcn_mfma_f32_16x16x32_f16(ahA, bh1[nt], accA[nt], 0, 0, 0);
            accA[nt] = __builtin_amdgcn_mfma_f32_16x16x32_f16(alA, bh1[nt], accA[nt], 0, 0, 0);
            accA[nt] = __builtin_amdgcn_mfma_f32_16x16x32_f16(ahA, bl1[nt], accA[nt], 0, 0, 0);
            accB[nt] = __builtin_amdgcn_mfma_f32_16x16x32_f16(ahB, bh1[nt], accB[nt], 0, 0, 0);
            accB[nt] = __builtin_amdgcn_mfma_f32_16x16x32_f16(alB, bh1[nt], accB[nt], 0, 0, 0);
            accB[nt] = __builtin_amdgcn_mfma_f32_16x16x32_f16(ahB, bl1[nt], accB[nt], 0, 0, 0);
        }
    }

    // ---- stage partial accumulators to LDS (lane-contiguous => conflict-free)
    #pragma unroll
    for (int nt = 0; nt < 4; nt++) {
        sacc[wid][0][nt][lane] = accA[nt];
        sacc[wid][1][nt][lane] = accB[nt];
    }
    __syncthreads();

    // ---- epilogue: wave 0 -> tokenset 0, wave 1 -> tokenset 1
    if (wid < 2) {
        const int ts = wid;
        f32x4 zv[4];
        #pragma unroll
        for (int nt = 0; nt < 4; nt++) {
            f32x4 s = sacc[0][ts][nt][lane];
            #pragma unroll
            for (int w = 1; w < NWAVE; w++) s += sacc[w][ts][nt][lane]; // k-order
            zv[nt] = s;
        }

        float gb[4], eb[4];
        #pragma unroll
        for (int nt = 0; nt < 4; nt++) {
            gb[nt] = gbias[nt * 16 + col];
            eb[nt] = ebias[nt * 16 + col];
        }

        #pragma unroll
        for (int r = 0; r < 4; r++) {
            const int t = tok0 + ts * 16 + q * 4 + r;   // C layout: row = q*4+reg
            float z[4], sel[4];
            #pragma unroll
            for (int nt = 0; nt < 4; nt++) {
                z[nt]   = zv[nt][r] + gb[nt];
                sel[nt] = z[nt] + eb[nt];
            }

            int idxs[TOPK]; float probs[TOPK]; float psum = 0.f;
            #pragma unroll
            for (int rr = 0; rr < TOPK; rr++) {
                float bv = -INFINITY, bz = 0.f; int bidx = 1 << 30;
                #pragma unroll
                for (int nt = 0; nt < 4; nt++)
                    if (sel[nt] > bv) { bv = sel[nt]; bz = z[nt]; bidx = nt * 16 + col; }
                #pragma unroll
                for (int m = 1; m < 16; m <<= 1) {   // xor<16 stays in 16-lane group
                    float ov = __shfl_xor(bv, m);
                    float oz = __shfl_xor(bz, m);
                    int   oi = __shfl_xor(bidx, m);
                    if (ov > bv || (ov == bv && oi < bidx)) { bv = ov; bz = oz; bidx = oi; }
                }
                idxs[rr] = bidx;
                float p = 1.f / (1.f + expf(-bz));
                probs[rr] = p; psum += p;
                if ((bidx & 15) == col) sel[bidx >> 4] = -INFINITY;   // mark used
            }
            float inv = 1.f / psum;
            if (col < TOPK) {
                out[(size_t)t * TOPK + col] = (float)idxs[col];
                out[(size_t)NTOK * TOPK + (size_t)t * TOPK + col] = probs[col] * inv;
                if (mask[t] != 0) atomicAdd(&cnt[idxs[col]], 1u);
            }
        }
    }
    __syncthreads();
    if (tid < NEXP)
        blockcnt[(size_t)blockIdx.x * NEXP + tid] = (float)cnt[tid];
}

// ============================================================================
// Kernel 3: tree-sum per-block counts -> maxvio. One block, 256 threads.
// ============================================================================
__global__ __launch_bounds__(256) void finalize_kernel(
    const float* __restrict__ blockcnt, float* __restrict__ out)
{
    __shared__ float ps[4][NEXP];
    const int t = threadIdx.x;
    const int e = t & 63, c = t >> 6;
    float s = 0.f;
    #pragma unroll 8
    for (int b = 0; b < GBLK / 4; b++)
        s += blockcnt[(size_t)(c * (GBLK / 4) + b) * NEXP + e];
    ps[c][e] = s;
    __syncthreads();
    if (t < 64) {
        float tot = ps[0][t] + ps[1][t] + ps[2][t] + ps[3][t];
        float mx = tot, sm = tot;
        #pragma unroll
        for (int o = 32; o > 0; o >>= 1) {
            mx = fmaxf(mx, __shfl_down(mx, o));
            sm += __shfl_down(sm, o);
        }
        if (t == 0) {
            float avg = sm / (float)NEXP;
            out[2 * NTOK * TOPK] = (mx - avg) / (avg + 1e-5f);
        }
    }
}

// ============================================================================
// Fallback for tiny workspace: R1 fused fp32 kernel (known-correct).
// ============================================================================
__global__ __launch_bounds__(256) void fused_fallback_kernel(
    const float* __restrict__ x, const int* __restrict__ mask,
    const float* __restrict__ W, const float* __restrict__ gbias,
    const float* __restrict__ ebias, float* __restrict__ out,
    unsigned int* __restrict__ counts)
{
    __shared__ float As[64][36];
    __shared__ float Bs[64][36];
    __shared__ float Lg[64][NEXP + 1];
    __shared__ float s_gb[NEXP], s_eb[NEXP];
    __shared__ unsigned int s_cnt[NEXP];
    const int tid = threadIdx.x;
    const int tx = tid & 15, ty = tid >> 4;
    const int m0 = blockIdx.x * 64;
    if (tid < NEXP) { s_gb[tid] = gbias[tid]; s_eb[tid] = ebias[tid]; s_cnt[tid] = 0u; }
    float acc[4][4] = {};
    for (int kb = 0; kb < CDIM; kb += 32) {
        __syncthreads();
        #pragma unroll
        for (int p = 0; p < 2; p++) {
            int lin = tid + p * 256; int m = lin >> 3; int c4 = (lin & 7) << 2;
            *(float4*)&As[m][c4] = *(const float4*)&x[(size_t)(m0 + m) * CDIM + kb + c4];
            *(float4*)&Bs[m][c4] = *(const float4*)&W[(size_t)m * CDIM + kb + c4];
        }
        __syncthreads();
        #pragma unroll
        for (int k4 = 0; k4 < 32; k4 += 4) {
            float4 a[4], b[4];
            #pragma unroll
            for (int i = 0; i < 4; i++) a[i] = *(const float4*)&As[ty * 4 + i][k4];
            #pragma unroll
            for (int j = 0; j < 4; j++) b[j] = *(const float4*)&Bs[tx * 4 + j][k4];
            #pragma unroll
            for (int i = 0; i < 4; i++)
                #pragma unroll
                for (int j = 0; j < 4; j++)
                    acc[i][j] += a[i].x * b[j].x + a[i].y * b[j].y
                               + a[i].z * b[j].z + a[i].w * b[j].w;
        }
    }
    __syncthreads();
    #pragma unroll
    for (int i = 0; i < 4; i++)
        #pragma unroll
        for (int j = 0; j < 4; j++)
            Lg[ty * 4 + i][tx * 4 + j] = acc[i][j] + s_gb[tx * 4 + j];
    __syncthreads();
    if (tid < 64) {
        const int g = m0 + tid;
        unsigned long long used = 0ull;
        int idxs[TOPK]; float probs[TOPK]; float psum = 0.f;
        #pragma unroll
        for (int k = 0; k < TOPK; k++) {
            float best = -INFINITY; int bi = 0;
            for (int n = 0; n < NEXP; n++) {
                if ((used >> n) & 1ull) continue;
                float vv = Lg[tid][n] + s_eb[n];
                if (vv > best) { best = vv; bi = n; }
            }
            used |= (1ull << bi);
            idxs[k] = bi;
            float p = 1.f / (1.f + expf(-Lg[tid][bi]));
            probs[k] = p; psum += p;
        }
        float inv = 1.f / psum;
        #pragma unroll
        for (int k = 0; k < TOPK; k++) {
            out[(size_t)g * TOPK + k] = (float)idxs[k];
            out[(size_t)NTOK * TOPK + (size_t)g * TOPK + k] = probs[k] * inv;
        }
        if (mask[g] != 0)
            #pragma unroll
            for (int k = 0; k < TOPK; k++) atomicAdd(&s_cnt[idxs[k]], 1u);
    }
    __syncthreads();
    if (tid < NEXP && s_cnt[tid] != 0u) atomicAdd(&counts[tid], s_cnt[tid]);
}

__global__ void finalize_atomic_kernel(const unsigned int* __restrict__ counts,
                                       float* __restrict__ out)
{
    const int t = threadIdx.x;
    float c  = (float)counts[t];
    float mx = c, sm = c;
    #pragma unroll
    for (int o = 32; o > 0; o >>= 1) {
        mx = fmaxf(mx, __shfl_down(mx, o));
        sm += __shfl_down(sm, o);
    }
    if (t == 0) {
        float avg = sm / (float)NEXP;
        out[2 * NTOK * TOPK] = (mx - avg) / (avg + 1e-5f);
    }
}

extern "C" void kernel_launch(void* const* d_in, const int* in_sizes, int n_in,
                              void* d_out, int out_size, void* d_ws, size_t ws_size,
                              hipStream_t stream)
{
    const float* x     = (const float*)d_in[0];
    const int*   mask  = (const int*)  d_in[1];
    const float* W     = (const float*)d_in[2];
    const float* gbias = (const float*)d_in[3];
    const float* ebias = (const float*)d_in[4];
    float* out = (float*)d_out;

    // ws layout: [Wh 256KB][Wl 256KB][blockcnt 128KB]
    const size_t whB  = (size_t)NEXP * CDIM * sizeof(_Float16);   // 256 KB
    const size_t bcB  = (size_t)GBLK * NEXP * sizeof(float);      // 128 KB
    const size_t need = 2 * whB + bcB;

    if (ws_size >= need) {
        _Float16* Wh = (_Float16*)d_ws;
        _Float16* Wl = (_Float16*)((char*)d_ws + whB);
        float* blockcnt = (float*)((char*)d_ws + 2 * whB);

        pack_w16_kernel<<<64, 256, 0, stream>>>(W, Wh, Wl);
        gate_fused_kernel<<<GBLK, 512, 0, stream>>>(x, Wh, Wl, mask, gbias, ebias, out, blockcnt);
        finalize_kernel<<<1, 256, 0, stream>>>(blockcnt, out);
        return;
    }

    // Fallback: fused fp32 kernel + global-atomic counts
    unsigned int* counts = (unsigned int*)d_ws;
    hipMemsetAsync(d_ws, 0, NEXP * sizeof(unsigned int), stream);
    fused_fallback_kernel<<<NTOK / 64, 256, 0, stream>>>(x, mask, W, gbias, ebias, out, counts);
    finalize_atomic_kernel<<<1, 64, 0, stream>>>(counts, out);
}

// Round 5
// 221.079 us; speedup vs baseline: 1.2196x; 1.0499x over previous
//
#include <hip/hip_runtime.h>
#include <math.h>

// Problem constants (MoEGate: B=4,T=4096,C=2048,E=64,K=8)
#define NTOK   16384
#define CDIM   2048
#define NEXP   64
#define TOPK   8
#define TOKB   32            // tokens per block (2 MFMA row-tiles)
#define NWAVE  8             // waves per block (in-block k-split factor)
#define GBLK   (NTOK / TOKB) // 512 blocks
#define XPITCH 1040          // LDS row pitch (bytes): 1024 + 16 staggers banks

typedef _Float16 f16x8 __attribute__((ext_vector_type(8)));
typedef float    f32x4 __attribute__((ext_vector_type(4)));

// ============================================================================
// Kernel 1: pack W[64][2048] fp32 into f16 hi/lo images in MFMA B-fragment
// order. Entry t = ((s*4 + nt)*64 + lane): 8 f16 for (expert = nt*16+(lane&15),
// k = s*32 + (lane>>4)*8 + j). GEMM lane then loads one contiguous 16B chunk.
// ============================================================================
__global__ __launch_bounds__(256) void pack_w16_kernel(
    const float* __restrict__ W,
    _Float16* __restrict__ Wh, _Float16* __restrict__ Wl)
{
    int t    = blockIdx.x * 256 + threadIdx.x;   // 0..16383
    int lane = t & 63;
    int nt   = (t >> 6) & 3;
    int s    = t >> 8;                           // k32-step, 0..63
    int e    = nt * 16 + (lane & 15);
    int k    = s * 32 + (lane >> 4) * 8;
    const float* src = W + (size_t)e * CDIM + k;
    #pragma unroll
    for (int j = 0; j < 8; j++) {
        float x = src[j];
        _Float16 h = (_Float16)x;                // rte
        Wh[(size_t)t * 8 + j] = h;
        Wl[(size_t)t * 8 + j] = (_Float16)(x - (float)h);
    }
}

__device__ __forceinline__ void split_f16(
    const float4 v0, const float4 v1, f16x8& ah, f16x8& al)
{
    float xr[8] = {v0.x, v0.y, v0.z, v0.w, v1.x, v1.y, v1.z, v1.w};
    #pragma unroll
    for (int j = 0; j < 8; j++) {
        _Float16 h = (_Float16)xr[j];
        ah[j] = h;
        al[j] = (_Float16)(xr[j] - (float)h);    // exact residual
    }
}

// ============================================================================
// Kernel 2 (FUSED): phase-decoupled LDS-staged streaming + 8-way k-split.
// R12: R0/R3/R4 all showed waves ~97% memory-stalled with only ~1 step of
// x-loads in flight (register-anchored prefetch can't go deeper; R4 proved
// hand-hoisting without reg room just serializes). Restructure: per chunk c
// (256 floats of k), the block BATCH-stages its 32-token x-chunk to LDS —
// each wave issues 4 independent fully-contiguous 1-KB row loads (deep MLP,
// DRAM-friendly bursts) + its 8 W-frags, then one barrier, then the proven
// 24-MFMA consume step reads A-frags from LDS. k-split remap: wave w takes
// k-subslice w*32 of each chunk (W step S = c*8+wid; re-association is
// harmless at 1e-3 tol). LDS x-buffer rows at 1040-B pitch stagger bank
// bases -> even 8-sweep b128 reads (write side linear = conflict-free).
// The 33-KB x-buffer ALIASES the 64-KB sacc (dead until after the loop), so
// LDS stays 64 KB -> 2 blocks/CU, grid 512, 16 waves/CU, (512,4) 128-reg cap.
// Partials meet in sacc; waves 0/1 reduce + verified 16-lane shfl_xor top-8
// (strict >, lowest index wins ties = JAX). ZERO global atomics.
// ============================================================================
__global__ __launch_bounds__(512, 4) void gate_fused_kernel(
    const float* __restrict__ x,       // [NTOK][CDIM]
    const _Float16* __restrict__ Wh,   // packed image, 256 KB (L2-hot)
    const _Float16* __restrict__ Wl,   // packed image, 256 KB (L2-hot)
    const int*   __restrict__ mask,    // [NTOK]
    const float* __restrict__ gbias,   // [NEXP]
    const float* __restrict__ ebias,   // [NEXP]
    float*       __restrict__ out,     // [2*NTOK*TOPK + 1]
    float*       __restrict__ blockcnt)// [GBLK][NEXP]
{
    __shared__ f32x4 sacc[NWAVE][2][4][64];  // 64 KB; first 33280 B alias = x-stage
    __shared__ unsigned int cnt[NEXP];
    char* lds_x = (char*)sacc;               // [32 rows][XPITCH] staging buffer

    const int tid  = threadIdx.x;
    const int lane = tid & 63;
    const int wid  = tid >> 6;               // 0..7
    if (tid < NEXP) cnt[tid] = 0u;

    const int tok0 = blockIdx.x * TOKB;
    const int col  = lane & 15;              // token row for A / expert col for C
    const int q    = lane >> 4;              // quad
    const char* gx = (const char*)(x + (size_t)tok0 * CDIM);
    const f16x8* whp = (const f16x8*)Wh + lane;
    const f16x8* wlp = (const f16x8*)Wl + lane;

    f32x4 accA[4], accB[4];
    #pragma unroll
    for (int nt = 0; nt < 4; nt++) {
        accA[nt] = (f32x4){0.f, 0.f, 0.f, 0.f};
        accB[nt] = (f32x4){0.f, 0.f, 0.f, 0.f};
    }

    const int rowA = col, rowB = 16 + col;
    const unsigned offb = (unsigned)(wid * 128 + q * 32);

    for (int c = 0; c < 8; c++) {
        // ---- stage phase: 4 contiguous 1-KB x-row chunks per wave -> LDS ----
        float4 v0 = *(const float4*)(gx + (size_t)(wid * 4 + 0) * 8192 + c * 1024 + lane * 16);
        float4 v1 = *(const float4*)(gx + (size_t)(wid * 4 + 1) * 8192 + c * 1024 + lane * 16);
        float4 v2 = *(const float4*)(gx + (size_t)(wid * 4 + 2) * 8192 + c * 1024 + lane * 16);
        float4 v3 = *(const float4*)(gx + (size_t)(wid * 4 + 3) * 8192 + c * 1024 + lane * 16);

        // W frags for this chunk's step (L2-hot, no LDS dependency)
        const int S = c * 8 + wid;           // global k32-step
        f16x8 bh[4], bl[4];
        #pragma unroll
        for (int nt = 0; nt < 4; nt++) {
            bh[nt] = whp[(size_t)S * 256 + nt * 64];
            bl[nt] = wlp[(size_t)S * 256 + nt * 64];
        }

        *(float4*)(lds_x + (wid * 4 + 0) * XPITCH + lane * 16) = v0;
        *(float4*)(lds_x + (wid * 4 + 1) * XPITCH + lane * 16) = v1;
        *(float4*)(lds_x + (wid * 4 + 2) * XPITCH + lane * 16) = v2;
        *(float4*)(lds_x + (wid * 4 + 3) * XPITCH + lane * 16) = v3;
        __syncthreads();

        // ---- consume phase: A-frags from LDS, 24 MFMAs ----
        float4 a0 = *(const float4*)(lds_x + rowA * XPITCH + offb);
        float4 a1 = *(const float4*)(lds_x + rowA * XPITCH + offb + 16);
        float4 c0 = *(const float4*)(lds_x + rowB * XPITCH + offb);
        float4 c1 = *(const float4*)(lds_x + rowB * XPITCH + offb + 16);
        f16x8 ahA, alA, ahB, alB;
        split_f16(a0, a1, ahA, alA);
        split_f16(c0, c1, ahB, alB);
        #pragma unroll
        for (int nt = 0; nt < 4; nt++) {
            accA[nt] = __builtin_amdgcn_mfma_f32_16x16x32_f16(ahA, bh[nt], accA[nt], 0, 0, 0);
            accA[nt] = __builtin_amdgcn_mfma_f32_16x16x32_f16(alA, bh[nt], accA[nt], 0, 0, 0);
            accA[nt] = __builtin_amdgcn_mfma_f32_16x16x32_f16(ahA, bl[nt], accA[nt], 0, 0, 0);
            accB[nt] = __builtin_amdgcn_mfma_f32_16x16x32_f16(ahB, bh[nt], accB[nt], 0, 0, 0);
            accB[nt] = __builtin_amdgcn_mfma_f32_16x16x32_f16(alB, bh[nt], accB[nt], 0, 0, 0);
            accB[nt] = __builtin_amdgcn_mfma_f32_16x16x32_f16(ahB, bl[nt], accB[nt], 0, 0, 0);
        }
        __syncthreads();   // protect staging buffer before next chunk / sacc
    }

    // ---- stage partial accumulators to LDS (lane-contiguous => conflict-free)
    #pragma unroll
    for (int nt = 0; nt < 4; nt++) {
        sacc[wid][0][nt][lane] = accA[nt];
        sacc[wid][1][nt][lane] = accB[nt];
    }
    __syncthreads();

    // ---- epilogue: wave 0 -> tokenset 0, wave 1 -> tokenset 1
    if (wid < 2) {
        const int ts = wid;
        f32x4 zv[4];
        #pragma unroll
        for (int nt = 0; nt < 4; nt++) {
            f32x4 s = sacc[0][ts][nt][lane];
            #pragma unroll
            for (int w = 1; w < NWAVE; w++) s += sacc[w][ts][nt][lane];
            zv[nt] = s;
        }

        float gb[4], eb[4];
        #pragma unroll
        for (int nt = 0; nt < 4; nt++) {
            gb[nt] = gbias[nt * 16 + col];
            eb[nt] = ebias[nt * 16 + col];
        }

        #pragma unroll
        for (int r = 0; r < 4; r++) {
            const int t = tok0 + ts * 16 + q * 4 + r;   // C layout: row = q*4+reg
            float z[4], sel[4];
            #pragma unroll
            for (int nt = 0; nt < 4; nt++) {
                z[nt]   = zv[nt][r] + gb[nt];
                sel[nt] = z[nt] + eb[nt];
            }

            int idxs[TOPK]; float probs[TOPK]; float psum = 0.f;
            #pragma unroll
            for (int rr = 0; rr < TOPK; rr++) {
                float bv = -INFINITY, bz = 0.f; int bidx = 1 << 30;
                #pragma unroll
                for (int nt = 0; nt < 4; nt++)
                    if (sel[nt] > bv) { bv = sel[nt]; bz = z[nt]; bidx = nt * 16 + col; }
                #pragma unroll
                for (int m = 1; m < 16; m <<= 1) {   // xor<16 stays in 16-lane group
                    float ov = __shfl_xor(bv, m);
                    float oz = __shfl_xor(bz, m);
                    int   oi = __shfl_xor(bidx, m);
                    if (ov > bv || (ov == bv && oi < bidx)) { bv = ov; bz = oz; bidx = oi; }
                }
                idxs[rr] = bidx;
                float p = 1.f / (1.f + expf(-bz));
                probs[rr] = p; psum += p;
                if ((bidx & 15) == col) sel[bidx >> 4] = -INFINITY;   // mark used
            }
            float inv = 1.f / psum;
            if (col < TOPK) {
                out[(size_t)t * TOPK + col] = (float)idxs[col];
                out[(size_t)NTOK * TOPK + (size_t)t * TOPK + col] = probs[col] * inv;
                if (mask[t] != 0) atomicAdd(&cnt[idxs[col]], 1u);
            }
        }
    }
    __syncthreads();
    if (tid < NEXP)
        blockcnt[(size_t)blockIdx.x * NEXP + tid] = (float)cnt[tid];
}

// ============================================================================
// Kernel 3: tree-sum per-block counts -> maxvio. One block, 256 threads.
// ============================================================================
__global__ __launch_bounds__(256) void finalize_kernel(
    const float* __restrict__ blockcnt, float* __restrict__ out)
{
    __shared__ float ps[4][NEXP];
    const int t = threadIdx.x;
    const int e = t & 63, c = t >> 6;
    float s = 0.f;
    #pragma unroll 8
    for (int b = 0; b < GBLK / 4; b++)
        s += blockcnt[(size_t)(c * (GBLK / 4) + b) * NEXP + e];
    ps[c][e] = s;
    __syncthreads();
    if (t < 64) {
        float tot = ps[0][t] + ps[1][t] + ps[2][t] + ps[3][t];
        float mx = tot, sm = tot;
        #pragma unroll
        for (int o = 32; o > 0; o >>= 1) {
            mx = fmaxf(mx, __shfl_down(mx, o));
            sm += __shfl_down(sm, o);
        }
        if (t == 0) {
            float avg = sm / (float)NEXP;
            out[2 * NTOK * TOPK] = (mx - avg) / (avg + 1e-5f);
        }
    }
}

// ============================================================================
// Fallback for tiny workspace: R1 fused fp32 kernel (known-correct).
// ============================================================================
__global__ __launch_bounds__(256) void fused_fallback_kernel(
    const float* __restrict__ x, const int* __restrict__ mask,
    const float* __restrict__ W, const float* __restrict__ gbias,
    const float* __restrict__ ebias, float* __restrict__ out,
    unsigned int* __restrict__ counts)
{
    __shared__ float As[64][36];
    __shared__ float Bs[64][36];
    __shared__ float Lg[64][NEXP + 1];
    __shared__ float s_gb[NEXP], s_eb[NEXP];
    __shared__ unsigned int s_cnt[NEXP];
    const int tid = threadIdx.x;
    const int tx = tid & 15, ty = tid >> 4;
    const int m0 = blockIdx.x * 64;
    if (tid < NEXP) { s_gb[tid] = gbias[tid]; s_eb[tid] = ebias[tid]; s_cnt[tid] = 0u; }
    float acc[4][4] = {};
    for (int kb = 0; kb < CDIM; kb += 32) {
        __syncthreads();
        #pragma unroll
        for (int p = 0; p < 2; p++) {
            int lin = tid + p * 256; int m = lin >> 3; int c4 = (lin & 7) << 2;
            *(float4*)&As[m][c4] = *(const float4*)&x[(size_t)(m0 + m) * CDIM + kb + c4];
            *(float4*)&Bs[m][c4] = *(const float4*)&W[(size_t)m * CDIM + kb + c4];
        }
        __syncthreads();
        #pragma unroll
        for (int k4 = 0; k4 < 32; k4 += 4) {
            float4 a[4], b[4];
            #pragma unroll
            for (int i = 0; i < 4; i++) a[i] = *(const float4*)&As[ty * 4 + i][k4];
            #pragma unroll
            for (int j = 0; j < 4; j++) b[j] = *(const float4*)&Bs[tx * 4 + j][k4];
            #pragma unroll
            for (int i = 0; i < 4; i++)
                #pragma unroll
                for (int j = 0; j < 4; j++)
                    acc[i][j] += a[i].x * b[j].x + a[i].y * b[j].y
                               + a[i].z * b[j].z + a[i].w * b[j].w;
        }
    }
    __syncthreads();
    #pragma unroll
    for (int i = 0; i < 4; i++)
        #pragma unroll
        for (int j = 0; j < 4; j++)
            Lg[ty * 4 + i][tx * 4 + j] = acc[i][j] + s_gb[tx * 4 + j];
    __syncthreads();
    if (tid < 64) {
        const int g = m0 + tid;
        unsigned long long used = 0ull;
        int idxs[TOPK]; float probs[TOPK]; float psum = 0.f;
        #pragma unroll
        for (int k = 0; k < TOPK; k++) {
            float best = -INFINITY; int bi = 0;
            for (int n = 0; n < NEXP; n++) {
                if ((used >> n) & 1ull) continue;
                float vv = Lg[tid][n] + s_eb[n];
                if (vv > best) { best = vv; bi = n; }
            }
            used |= (1ull << bi);
            idxs[k] = bi;
            float p = 1.f / (1.f + expf(-Lg[tid][bi]));
            probs[k] = p; psum += p;
        }
        float inv = 1.f / psum;
        #pragma unroll
        for (int k = 0; k < TOPK; k++) {
            out[(size_t)g * TOPK + k] = (float)idxs[k];
            out[(size_t)NTOK * TOPK + (size_t)g * TOPK + k] = probs[k] * inv;
        }
        if (mask[g] != 0)
            #pragma unroll
            for (int k = 0; k < TOPK; k++) atomicAdd(&s_cnt[idxs[k]], 1u);
    }
    __syncthreads();
    if (tid < NEXP && s_cnt[tid] != 0u) atomicAdd(&counts[tid], s_cnt[tid]);
}

__global__ void finalize_atomic_kernel(const unsigned int* __restrict__ counts,
                                       float* __restrict__ out)
{
    const int t = threadIdx.x;
    float c  = (float)counts[t];
    float mx = c, sm = c;
    #pragma unroll
    for (int o = 32; o > 0; o >>= 1) {
        mx = fmaxf(mx, __shfl_down(mx, o));
        sm += __shfl_down(sm, o);
    }
    if (t == 0) {
        float avg = sm / (float)NEXP;
        out[2 * NTOK * TOPK] = (mx - avg) / (avg + 1e-5f);
    }
}

extern "C" void kernel_launch(void* const* d_in, const int* in_sizes, int n_in,
                              void* d_out, int out_size, void* d_ws, size_t ws_size,
                              hipStream_t stream)
{
    const float* x     = (const float*)d_in[0];
    const int*   mask  = (const int*)  d_in[1];
    const float* W     = (const float*)d_in[2];
    const float* gbias = (const float*)d_in[3];
    const float* ebias = (const float*)d_in[4];
    float* out = (float*)d_out;

    // ws layout: [Wh 256KB][Wl 256KB][blockcnt 128KB]
    const size_t whB  = (size_t)NEXP * CDIM * sizeof(_Float16);   // 256 KB
    const size_t bcB  = (size_t)GBLK * NEXP * sizeof(float);      // 128 KB
    const size_t need = 2 * whB + bcB;

    if (ws_size >= need) {
        _Float16* Wh = (_Float16*)d_ws;
        _Float16* Wl = (_Float16*)((char*)d_ws + whB);
        float* blockcnt = (float*)((char*)d_ws + 2 * whB);

        pack_w16_kernel<<<64, 256, 0, stream>>>(W, Wh, Wl);
        gate_fused_kernel<<<GBLK, 512, 0, stream>>>(x, Wh, Wl, mask, gbias, ebias, out, blockcnt);
        finalize_kernel<<<1, 256, 0, stream>>>(blockcnt, out);
        return;
    }

    // Fallback: fused fp32 kernel + global-atomic counts
    unsigned int* counts = (unsigned int*)d_ws;
    hipMemsetAsync(d_ws, 0, NEXP * sizeof(unsigned int), stream);
    fused_fallback_kernel<<<NTOK / 64, 256, 0, stream>>>(x, mask, W, gbias, ebias, out, counts);
    finalize_atomic_kernel<<<1, 64, 0, stream>>>(counts, out);
}

// Round 6
// 219.911 us; speedup vs baseline: 1.2261x; 1.0053x over previous
//
#include <hip/hip_runtime.h>
#include <math.h>

// Problem constants (MoEGate: B=4,T=4096,C=2048,E=64,K=8)
#define NTOK   16384
#define CDIM   2048
#define NEXP   64
#define TOPK   8
#define TOKB   32            // tokens per block (2 MFMA row-tiles)
#define NWAVE  8             // waves per block (in-block k-split factor)
#define GBLK   (NTOK / TOKB) // 512 blocks
#define XPITCH 1040          // LDS row pitch (bytes): 1024 + 16 staggers banks

typedef _Float16 f16x8 __attribute__((ext_vector_type(8)));
typedef float    f32x4 __attribute__((ext_vector_type(4)));
typedef const __attribute__((address_space(1))) void* gas_t;
typedef __attribute__((address_space(3))) void* las_t;

// ============================================================================
// Kernel 1: pack W[64][2048] fp32 into f16 hi/lo images in MFMA B-fragment
// order. Entry t = ((s*4 + nt)*64 + lane): 8 f16 for (expert = nt*16+(lane&15),
// k = s*32 + (lane>>4)*8 + j). GEMM lane then loads one contiguous 16B chunk.
// ============================================================================
__global__ __launch_bounds__(256) void pack_w16_kernel(
    const float* __restrict__ W,
    _Float16* __restrict__ Wh, _Float16* __restrict__ Wl)
{
    int t    = blockIdx.x * 256 + threadIdx.x;   // 0..16383
    int lane = t & 63;
    int nt   = (t >> 6) & 3;
    int s    = t >> 8;                           // k32-step, 0..63
    int e    = nt * 16 + (lane & 15);
    int k    = s * 32 + (lane >> 4) * 8;
    const float* src = W + (size_t)e * CDIM + k;
    #pragma unroll
    for (int j = 0; j < 8; j++) {
        float x = src[j];
        _Float16 h = (_Float16)x;                // rte
        Wh[(size_t)t * 8 + j] = h;
        Wl[(size_t)t * 8 + j] = (_Float16)(x - (float)h);
    }
}

__device__ __forceinline__ void split_f16(
    const float4 v0, const float4 v1, f16x8& ah, f16x8& al)
{
    float xr[8] = {v0.x, v0.y, v0.z, v0.w, v1.x, v1.y, v1.z, v1.w};
    #pragma unroll
    for (int j = 0; j < 8; j++) {
        _Float16 h = (_Float16)xr[j];
        ah[j] = h;
        al[j] = (_Float16)(xr[j] - (float)h);    // exact residual
    }
}

// ============================================================================
// Kernel 2 (FUSED): pipelined LDS-staged streaming + 8-way k-split.
// R13: R12 (batch-stage to LDS, <77us, gate fell out of rocprof top-5) still
// exposed full HBM latency per chunk: global->reg->LDS round trip, serial
// stage->consume. Now: (1) global_load_lds direct staging (wave-uniform row
// base + per-lane global addr; our linear 1-KB rows match base+lane*16; the
// 1040-B row pitch survives since each call owns one whole row) — frees ~32
// VGPRs + LDS-write VALU; (2) chunk c+1's stage is issued right after the
// "all-waves-read-done" barrier, BEFORE split+MFMA of chunk c, so ~600cy of
// compute hides most of the ~900cy HBM latency. Ordering: W(c) loads issue
// BEFORE barrier#2 (its vmcnt(0) drain waits W, not the unissued stage);
// stage(c+1) issues after. Next barrier#1 drains the residue only. MFMA
// needs no vmcnt wait. LDS x-buffer (33 KB) aliases the dead 64-KB sacc ->
// 2 blocks/CU, grid 512, (512,4). Partials meet in sacc; waves 0/1 reduce
// (w-ascending, k-remap verified R5) + verified 16-lane shfl_xor top-8
// (strict >, lowest index wins ties = JAX). ZERO global atomics.
// ============================================================================
__global__ __launch_bounds__(512, 4) void gate_fused_kernel(
    const float* __restrict__ x,       // [NTOK][CDIM]
    const _Float16* __restrict__ Wh,   // packed image, 256 KB (L2-hot)
    const _Float16* __restrict__ Wl,   // packed image, 256 KB (L2-hot)
    const int*   __restrict__ mask,    // [NTOK]
    const float* __restrict__ gbias,   // [NEXP]
    const float* __restrict__ ebias,   // [NEXP]
    float*       __restrict__ out,     // [2*NTOK*TOPK + 1]
    float*       __restrict__ blockcnt)// [GBLK][NEXP]
{
    __shared__ f32x4 sacc[NWAVE][2][4][64];  // 64 KB; first 33280 B alias = x-stage
    __shared__ unsigned int cnt[NEXP];
    char* lds_x = (char*)sacc;               // [32 rows][XPITCH] staging buffer

    const int tid  = threadIdx.x;
    const int lane = tid & 63;
    const int wid  = tid >> 6;               // 0..7
    if (tid < NEXP) cnt[tid] = 0u;

    const int tok0 = blockIdx.x * TOKB;
    const int col  = lane & 15;              // token row for A / expert col for C
    const int q    = lane >> 4;              // quad
    const char* gx = (const char*)(x + (size_t)tok0 * CDIM);
    const f16x8* whp = (const f16x8*)Wh + lane;
    const f16x8* wlp = (const f16x8*)Wl + lane;

    f32x4 accA[4], accB[4];
    #pragma unroll
    for (int nt = 0; nt < 4; nt++) {
        accA[nt] = (f32x4){0.f, 0.f, 0.f, 0.f};
        accB[nt] = (f32x4){0.f, 0.f, 0.f, 0.f};
    }

    const int rowA = col, rowB = 16 + col;
    const unsigned offb = (unsigned)(wid * 128 + q * 32);

    // stage chunk c: 4 rows/wave, each row = 64 lanes x 16 B = 1 KB contiguous.
    // LDS dest = wave-uniform row base (HW adds lane*16); global src per-lane.
    #define STAGE(c) do {                                                      \
        _Pragma("unroll")                                                      \
        for (int i = 0; i < 4; i++) {                                          \
            const int row_ = wid * 4 + i;                                      \
            __builtin_amdgcn_global_load_lds(                                  \
                (gas_t)(gx + (size_t)row_ * 8192 + (c) * 1024 + lane * 16),    \
                (las_t)(lds_x + row_ * XPITCH),                                \
                16, 0, 0);                                                     \
        }                                                                      \
    } while (0)

    STAGE(0);                                // prologue: chunk 0 in flight

    #pragma unroll
    for (int c = 0; c < 8; c++) {
        __syncthreads();                     // barrier#1: vmcnt(0) drain => stage(c) landed

        // W frags for this chunk's k32-step (L2-hot). Issued BEFORE barrier#2
        // so its vmcnt(0) drain covers them (older than stage(c+1)).
        const int S = c * 8 + wid;           // global k32-step (k-remap, verified)
        f16x8 bh[4], bl[4];
        #pragma unroll
        for (int nt = 0; nt < 4; nt++) {
            bh[nt] = whp[(size_t)S * 256 + nt * 64];
            bl[nt] = wlp[(size_t)S * 256 + nt * 64];
        }

        // A-frags from LDS (staggered pitch => <=2-way bank alias, free)
        float4 a0 = *(const float4*)(lds_x + rowA * XPITCH + offb);
        float4 a1 = *(const float4*)(lds_x + rowA * XPITCH + offb + 16);
        float4 c0 = *(const float4*)(lds_x + rowB * XPITCH + offb);
        float4 c1 = *(const float4*)(lds_x + rowB * XPITCH + offb + 16);

        __syncthreads();                     // barrier#2: all waves done reading buffer

        if (c < 7) STAGE(c + 1);             // overlaps with split+MFMA below

        f16x8 ahA, alA, ahB, alB;
        split_f16(a0, a1, ahA, alA);
        split_f16(c0, c1, ahB, alB);
        #pragma unroll
        for (int nt = 0; nt < 4; nt++) {
            accA[nt] = __builtin_amdgcn_mfma_f32_16x16x32_f16(ahA, bh[nt], accA[nt], 0, 0, 0);
            accA[nt] = __builtin_amdgcn_mfma_f32_16x16x32_f16(alA, bh[nt], accA[nt], 0, 0, 0);
            accA[nt] = __builtin_amdgcn_mfma_f32_16x16x32_f16(ahA, bl[nt], accA[nt], 0, 0, 0);
            accB[nt] = __builtin_amdgcn_mfma_f32_16x16x32_f16(ahB, bh[nt], accB[nt], 0, 0, 0);
            accB[nt] = __builtin_amdgcn_mfma_f32_16x16x32_f16(alB, bh[nt], accB[nt], 0, 0, 0);
            accB[nt] = __builtin_amdgcn_mfma_f32_16x16x32_f16(ahB, bl[nt], accB[nt], 0, 0, 0);
        }
    }
    #undef STAGE

    // After barrier#2 of c=7 all x-buffer reads are done; sacc may be written.
    #pragma unroll
    for (int nt = 0; nt < 4; nt++) {
        sacc[wid][0][nt][lane] = accA[nt];
        sacc[wid][1][nt][lane] = accB[nt];
    }
    __syncthreads();

    // ---- epilogue: wave 0 -> tokenset 0, wave 1 -> tokenset 1
    if (wid < 2) {
        const int ts = wid;
        f32x4 zv[4];
        #pragma unroll
        for (int nt = 0; nt < 4; nt++) {
            f32x4 s = sacc[0][ts][nt][lane];
            #pragma unroll
            for (int w = 1; w < NWAVE; w++) s += sacc[w][ts][nt][lane];
            zv[nt] = s;
        }

        float gb[4], eb[4];
        #pragma unroll
        for (int nt = 0; nt < 4; nt++) {
            gb[nt] = gbias[nt * 16 + col];
            eb[nt] = ebias[nt * 16 + col];
        }

        #pragma unroll
        for (int r = 0; r < 4; r++) {
            const int t = tok0 + ts * 16 + q * 4 + r;   // C layout: row = q*4+reg
            float z[4], sel[4];
            #pragma unroll
            for (int nt = 0; nt < 4; nt++) {
                z[nt]   = zv[nt][r] + gb[nt];
                sel[nt] = z[nt] + eb[nt];
            }

            int idxs[TOPK]; float probs[TOPK]; float psum = 0.f;
            #pragma unroll
            for (int rr = 0; rr < TOPK; rr++) {
                float bv = -INFINITY, bz = 0.f; int bidx = 1 << 30;
                #pragma unroll
                for (int nt = 0; nt < 4; nt++)
                    if (sel[nt] > bv) { bv = sel[nt]; bz = z[nt]; bidx = nt * 16 + col; }
                #pragma unroll
                for (int m = 1; m < 16; m <<= 1) {   // xor<16 stays in 16-lane group
                    float ov = __shfl_xor(bv, m);
                    float oz = __shfl_xor(bz, m);
                    int   oi = __shfl_xor(bidx, m);
                    if (ov > bv || (ov == bv && oi < bidx)) { bv = ov; bz = oz; bidx = oi; }
                }
                idxs[rr] = bidx;
                float p = 1.f / (1.f + expf(-bz));
                probs[rr] = p; psum += p;
                if ((bidx & 15) == col) sel[bidx >> 4] = -INFINITY;   // mark used
            }
            float inv = 1.f / psum;
            if (col < TOPK) {
                out[(size_t)t * TOPK + col] = (float)idxs[col];
                out[(size_t)NTOK * TOPK + (size_t)t * TOPK + col] = probs[col] * inv;
                if (mask[t] != 0) atomicAdd(&cnt[idxs[col]], 1u);
            }
        }
    }
    __syncthreads();
    if (tid < NEXP)
        blockcnt[(size_t)blockIdx.x * NEXP + tid] = (float)cnt[tid];
}

// ============================================================================
// Kernel 3: tree-sum per-block counts -> maxvio. One block, 256 threads.
// ============================================================================
__global__ __launch_bounds__(256) void finalize_kernel(
    const float* __restrict__ blockcnt, float* __restrict__ out)
{
    __shared__ float ps[4][NEXP];
    const int t = threadIdx.x;
    const int e = t & 63, c = t >> 6;
    float s = 0.f;
    #pragma unroll 8
    for (int b = 0; b < GBLK / 4; b++)
        s += blockcnt[(size_t)(c * (GBLK / 4) + b) * NEXP + e];
    ps[c][e] = s;
    __syncthreads();
    if (t < 64) {
        float tot = ps[0][t] + ps[1][t] + ps[2][t] + ps[3][t];
        float mx = tot, sm = tot;
        #pragma unroll
        for (int o = 32; o > 0; o >>= 1) {
            mx = fmaxf(mx, __shfl_down(mx, o));
            sm += __shfl_down(sm, o);
        }
        if (t == 0) {
            float avg = sm / (float)NEXP;
            out[2 * NTOK * TOPK] = (mx - avg) / (avg + 1e-5f);
        }
    }
}

// ============================================================================
// Fallback for tiny workspace: R1 fused fp32 kernel (known-correct).
// ============================================================================
__global__ __launch_bounds__(256) void fused_fallback_kernel(
    const float* __restrict__ x, const int* __restrict__ mask,
    const float* __restrict__ W, const float* __restrict__ gbias,
    const float* __restrict__ ebias, float* __restrict__ out,
    unsigned int* __restrict__ counts)
{
    __shared__ float As[64][36];
    __shared__ float Bs[64][36];
    __shared__ float Lg[64][NEXP + 1];
    __shared__ float s_gb[NEXP], s_eb[NEXP];
    __shared__ unsigned int s_cnt[NEXP];
    const int tid = threadIdx.x;
    const int tx = tid & 15, ty = tid >> 4;
    const int m0 = blockIdx.x * 64;
    if (tid < NEXP) { s_gb[tid] = gbias[tid]; s_eb[tid] = ebias[tid]; s_cnt[tid] = 0u; }
    float acc[4][4] = {};
    for (int kb = 0; kb < CDIM; kb += 32) {
        __syncthreads();
        #pragma unroll
        for (int p = 0; p < 2; p++) {
            int lin = tid + p * 256; int m = lin >> 3; int c4 = (lin & 7) << 2;
            *(float4*)&As[m][c4] = *(const float4*)&x[(size_t)(m0 + m) * CDIM + kb + c4];
            *(float4*)&Bs[m][c4] = *(const float4*)&W[(size_t)m * CDIM + kb + c4];
        }
        __syncthreads();
        #pragma unroll
        for (int k4 = 0; k4 < 32; k4 += 4) {
            float4 a[4], b[4];
            #pragma unroll
            for (int i = 0; i < 4; i++) a[i] = *(const float4*)&As[ty * 4 + i][k4];
            #pragma unroll
            for (int j = 0; j < 4; j++) b[j] = *(const float4*)&Bs[tx * 4 + j][k4];
            #pragma unroll
            for (int i = 0; i < 4; i++)
                #pragma unroll
                for (int j = 0; j < 4; j++)
                    acc[i][j] += a[i].x * b[j].x + a[i].y * b[j].y
                               + a[i].z * b[j].z + a[i].w * b[j].w;
        }
    }
    __syncthreads();
    #pragma unroll
    for (int i = 0; i < 4; i++)
        #pragma unroll
        for (int j = 0; j < 4; j++)
            Lg[ty * 4 + i][tx * 4 + j] = acc[i][j] + s_gb[tx * 4 + j];
    __syncthreads();
    if (tid < 64) {
        const int g = m0 + tid;
        unsigned long long used = 0ull;
        int idxs[TOPK]; float probs[TOPK]; float psum = 0.f;
        #pragma unroll
        for (int k = 0; k < TOPK; k++) {
            float best = -INFINITY; int bi = 0;
            for (int n = 0; n < NEXP; n++) {
                if ((used >> n) & 1ull) continue;
                float vv = Lg[tid][n] + s_eb[n];
                if (vv > best) { best = vv; bi = n; }
            }
            used |= (1ull << bi);
            idxs[k] = bi;
            float p = 1.f / (1.f + expf(-Lg[tid][bi]));
            probs[k] = p; psum += p;
        }
        float inv = 1.f / psum;
        #pragma unroll
        for (int k = 0; k < TOPK; k++) {
            out[(size_t)g * TOPK + k] = (float)idxs[k];
            out[(size_t)NTOK * TOPK + (size_t)g * TOPK + k] = probs[k] * inv;
        }
        if (mask[g] != 0)
            #pragma unroll
            for (int k = 0; k < TOPK; k++) atomicAdd(&s_cnt[idxs[k]], 1u);
    }
    __syncthreads();
    if (tid < NEXP && s_cnt[tid] != 0u) atomicAdd(&counts[tid], s_cnt[tid]);
}

__global__ void finalize_atomic_kernel(const unsigned int* __restrict__ counts,
                                       float* __restrict__ out)
{
    const int t = threadIdx.x;
    float c  = (float)counts[t];
    float mx = c, sm = c;
    #pragma unroll
    for (int o = 32; o > 0; o >>= 1) {
        mx = fmaxf(mx, __shfl_down(mx, o));
        sm += __shfl_down(sm, o);
    }
    if (t == 0) {
        float avg = sm / (float)NEXP;
        out[2 * NTOK * TOPK] = (mx - avg) / (avg + 1e-5f);
    }
}

extern "C" void kernel_launch(void* const* d_in, const int* in_sizes, int n_in,
                              void* d_out, int out_size, void* d_ws, size_t ws_size,
                              hipStream_t stream)
{
    const float* x     = (const float*)d_in[0];
    const int*   mask  = (const int*)  d_in[1];
    const float* W     = (const float*)d_in[2];
    const float* gbias = (const float*)d_in[3];
    const float* ebias = (const float*)d_in[4];
    float* out = (float*)d_out;

    // ws layout: [Wh 256KB][Wl 256KB][blockcnt 128KB]
    const size_t whB  = (size_t)NEXP * CDIM * sizeof(_Float16);   // 256 KB
    const size_t bcB  = (size_t)GBLK * NEXP * sizeof(float);      // 128 KB
    const size_t need = 2 * whB + bcB;

    if (ws_size >= need) {
        _Float16* Wh = (_Float16*)d_ws;
        _Float16* Wl = (_Float16*)((char*)d_ws + whB);
        float* blockcnt = (float*)((char*)d_ws + 2 * whB);

        pack_w16_kernel<<<64, 256, 0, stream>>>(W, Wh, Wl);
        gate_fused_kernel<<<GBLK, 512, 0, stream>>>(x, Wh, Wl, mask, gbias, ebias, out, blockcnt);
        finalize_kernel<<<1, 256, 0, stream>>>(blockcnt, out);
        return;
    }

    // Fallback: fused fp32 kernel + global-atomic counts
    unsigned int* counts = (unsigned int*)d_ws;
    hipMemsetAsync(d_ws, 0, NEXP * sizeof(unsigned int), stream);
    fused_fallback_kernel<<<NTOK / 64, 256, 0, stream>>>(x, mask, W, gbias, ebias, out, counts);
    finalize_atomic_kernel<<<1, 64, 0, stream>>>(counts, out);
}